// Round 2
// baseline (257.355 us; speedup 1.0000x reference)
//
#include <hip/hip_runtime.h>
#include <hip/hip_bf16.h>

#define NN 8192
#define FF 128

typedef __attribute__((ext_vector_type(8))) short bf16x8;   // 8 bf16 (4 VGPR) MFMA frag
typedef __attribute__((ext_vector_type(4))) float f32x4;

__device__ __forceinline__ short f2bf(float f) {
  // round-to-nearest-even f32 -> bf16 (inputs finite)
  unsigned u = __float_as_uint(f);
  u += 0x7FFFu + ((u >> 16) & 1u);
  return (short)(u >> 16);
}
__device__ __forceinline__ float bf2f(short s) {
  return __uint_as_float(((unsigned)(unsigned short)s) << 16);
}

// ---- kernel 1: deg/dinv from f32 rowsums AND write bf16 copy of adj to ws ----
__global__ __launch_bounds__(256) void k_deg_cvt(const float* __restrict__ adj,
                                                 float* __restrict__ dinv,
                                                 short* __restrict__ abf) {
  const int row = blockIdx.x;
  const float4* p = (const float4*)(adj + (size_t)row * NN);
  short4* q = (short4*)(abf + (size_t)row * NN);
  float s = 0.f;
#pragma unroll
  for (int it = 0; it < 8; ++it) {
    float4 v = p[it * 256 + threadIdx.x];
    s += (v.x + v.y) + (v.z + v.w);
    short4 o;
    o.x = f2bf(v.x); o.y = f2bf(v.y); o.z = f2bf(v.z); o.w = f2bf(v.w);
    q[it * 256 + threadIdx.x] = o;
  }
#pragma unroll
  for (int off = 32; off > 0; off >>= 1) s += __shfl_down(s, off, 64);
  __shared__ float partial[4];
  if ((threadIdx.x & 63) == 0) partial[threadIdx.x >> 6] = s;
  __syncthreads();
  if (threadIdx.x == 0) {
    float deg = (partial[0] + partial[1]) + (partial[2] + partial[3]) + 1.0f;
    dinv[row] = 1.0f / sqrtf(deg + 1e-8f);
  }
}

// ---- kernel 2: yT[f][i] = dinv[i] * x[i][f]  (bf16, transposed for NT GEMM) ----
__global__ __launch_bounds__(256) void k_scale_t(const float* __restrict__ x,
                                                 const float* __restrict__ dinv,
                                                 short* __restrict__ yT) {
  __shared__ float tile[64][129];
  const int r0 = blockIdx.x * 64;
  const int tid = threadIdx.x;
#pragma unroll
  for (int it = 0; it < 8; ++it) {
    int q = it * 256 + tid;     // float4 index in [0,2048)
    int r = q >> 5;             // 32 float4 per row
    int c = q & 31;
    float4 v = ((const float4*)(x + (size_t)(r0 + r) * FF))[c];
    float d = dinv[r0 + r];
    tile[r][c * 4 + 0] = v.x * d;
    tile[r][c * 4 + 1] = v.y * d;
    tile[r][c * 4 + 2] = v.z * d;
    tile[r][c * 4 + 3] = v.w * d;
  }
  __syncthreads();
  const int f = tid >> 1;
  const int i0 = (tid & 1) * 32;
#pragma unroll
  for (int g = 0; g < 4; ++g) {
    bf16x8 o;
#pragma unroll
    for (int j = 0; j < 8; ++j) o[j] = f2bf(tile[i0 + g * 8 + j][f]);
    *(bf16x8*)(yT + (size_t)f * NN + r0 + i0 + g * 8) = o;
  }
}

// ---- kernel 3: z = dinv * (adj @ y + y). Barrier-free, LDS-free MFMA GEMM. ----
// 256 blocks x 8 waves. Each wave owns a 32-row x 16-col output tile; all 8
// waves of a block share the same 32 A-rows (L1 reuse). A/B MFMA fragments are
// loaded straight from global (bf16) through a 4-stage register pipeline.
#define PF 4
__global__ __launch_bounds__(512) void k_gemm(const short* __restrict__ abf,
                                              const short* __restrict__ yT,
                                              const float* __restrict__ dinv,
                                              float* __restrict__ z) {
  const int tid = threadIdx.x;
  const int wave = tid >> 6;
  const int lane = tid & 63;
  const int row0 = blockIdx.x * 32;
  const int col0 = wave * 16;
  const int fr = lane & 15;
  const int kh = (lane >> 4) * 8;

  const short* pa0 = abf + (size_t)(row0 + fr) * NN + kh;        // rows 0..15 of tile
  const short* pa1 = pa0 + (size_t)16 * NN;                      // rows 16..31
  const short* pb  = yT  + (size_t)(col0 + fr) * NN + kh;

  f32x4 acc0 = {0.f, 0.f, 0.f, 0.f};
  f32x4 acc1 = {0.f, 0.f, 0.f, 0.f};

  bf16x8 A0[PF], A1[PF], B[PF];
#pragma unroll
  for (int s = 0; s < PF; ++s) {
    A0[s] = *(const bf16x8*)(pa0 + s * 32);
    A1[s] = *(const bf16x8*)(pa1 + s * 32);
    B[s]  = *(const bf16x8*)(pb  + s * 32);
  }

  for (int k0 = 0; k0 < NN; k0 += PF * 32) {
#pragma unroll
    for (int s = 0; s < PF; ++s) {
      bf16x8 a0 = A0[s], a1 = A1[s], b = B[s];
      int kn = k0 + (s + PF) * 32;
      if (kn < NN) {            // wave-uniform guard; loads issue under the MFMAs
        A0[s] = *(const bf16x8*)(pa0 + kn);
        A1[s] = *(const bf16x8*)(pa1 + kn);
        B[s]  = *(const bf16x8*)(pb  + kn);
      }
      acc0 = __builtin_amdgcn_mfma_f32_16x16x32_bf16(a0, b, acc0, 0, 0, 0);
      acc1 = __builtin_amdgcn_mfma_f32_16x16x32_bf16(a1, b, acc1, 0, 0, 0);
    }
  }

  // epilogue: + identity term, * dinv[row]; D layout: col=lane&15, row=(lane>>4)*4+r
  const int r4 = (lane >> 4) * 4;
  const int gf = col0 + fr;
#pragma unroll
  for (int r = 0; r < 4; ++r) {
    int gi = row0 + r4 + r;
    float t0 = acc0[r] + bf2f(yT[(size_t)gf * NN + gi]);
    z[(size_t)gi * FF + gf] = dinv[gi] * t0;
    int gj = gi + 16;
    float t1 = acc1[r] + bf2f(yT[(size_t)gf * NN + gj]);
    z[(size_t)gj * FF + gf] = dinv[gj] * t1;
  }
}

// ---- kernel 4: out = relu(z @ W), in place on d_out (z staged in LDS first) ----
__global__ __launch_bounds__(256) void k_wgemm(float* __restrict__ zo,
                                               const float* __restrict__ w) {
  __shared__ float zs[16][128];
  const int r0 = blockIdx.x * 16;
  const int tid = threadIdx.x;
#pragma unroll
  for (int it = 0; it < 2; ++it) {
    int q = it * 256 + tid;
    int r = q >> 5;
    int c = q & 31;
    float4 v = ((const float4*)(zo + (size_t)(r0 + r) * FF))[c];
    zs[r][c * 4 + 0] = v.x;
    zs[r][c * 4 + 1] = v.y;
    zs[r][c * 4 + 2] = v.z;
    zs[r][c * 4 + 3] = v.w;
  }
  __syncthreads();
  const int f = tid & 127;
  const int rg = (tid >> 7) * 8;
  float acc[8] = {0.f, 0.f, 0.f, 0.f, 0.f, 0.f, 0.f, 0.f};
#pragma unroll 4
  for (int k = 0; k < 128; ++k) {
    float wv = w[k * FF + f];
#pragma unroll
    for (int r = 0; r < 8; ++r) acc[r] += zs[rg + r][k] * wv;
  }
#pragma unroll
  for (int r = 0; r < 8; ++r) {
    zo[(size_t)(r0 + rg + r) * FF + f] = fmaxf(acc[r], 0.0f);
  }
}

extern "C" void kernel_launch(void* const* d_in, const int* in_sizes, int n_in,
                              void* d_out, int out_size, void* d_ws, size_t ws_size,
                              hipStream_t stream) {
  const float* x   = (const float*)d_in[0];
  const float* adj = (const float*)d_in[1];
  const float* w   = (const float*)d_in[2];
  float* out = (float*)d_out;

  float* dinv = (float*)d_ws;                                   // 32 KiB
  short* yT   = (short*)((char*)d_ws + 8192 * sizeof(float));   // 2 MiB bf16 [128][8192]
  short* abf  = (short*)((char*)d_ws + 4 * 1024 * 1024);        // 128 MiB bf16 [8192][8192]

  k_deg_cvt<<<NN,      256, 0, stream>>>(adj, dinv, abf);
  k_scale_t<<<NN / 64, 256, 0, stream>>>(x, dinv, yT);
  k_gemm   <<<NN / 32, 512, 0, stream>>>(abf, yT, dinv, out);
  k_wgemm  <<<NN / 16, 256, 0, stream>>>(out, w);
}

// Round 3
// 122.200 us; speedup vs baseline: 2.1060x; 2.1060x over previous
//
#include <hip/hip_runtime.h>
#include <hip/hip_bf16.h>

#define NN 8192
#define FF 128
#define BM 64
#define BK 64
#define KS 8
#define KCH (NN / KS)      // 1024 K per block
#define NSTEP (KCH / BK)   // 16

typedef __attribute__((ext_vector_type(8))) short bf16x8;   // 8 bf16 (4 VGPR)
typedef __attribute__((ext_vector_type(4))) float f32x4;

__device__ __forceinline__ short f2bf(float f) {
  unsigned u = __float_as_uint(f);
  u += 0x7FFFu + ((u >> 16) & 1u);
  return (short)(u >> 16);
}
__device__ __forceinline__ float bf2f(short s) {
  return __uint_as_float(((unsigned)(unsigned short)s) << 16);
}

// ---- kernel 1: deg[i] = rowsum(adj)+1 ; dinv[i] = (deg+1e-8)^-0.5 ----
__global__ __launch_bounds__(256) void k_deg(const float* __restrict__ adj,
                                             float* __restrict__ dinv) {
  const int row = blockIdx.x;
  const float4* p = (const float4*)(adj + (size_t)row * NN);
  float s = 0.f;
#pragma unroll
  for (int it = 0; it < 8; ++it) {
    float4 v = p[it * 256 + threadIdx.x];
    s += (v.x + v.y) + (v.z + v.w);
  }
#pragma unroll
  for (int off = 32; off > 0; off >>= 1) s += __shfl_down(s, off, 64);
  __shared__ float partial[4];
  if ((threadIdx.x & 63) == 0) partial[threadIdx.x >> 6] = s;
  __syncthreads();
  if (threadIdx.x == 0) {
    float deg = (partial[0] + partial[1]) + (partial[2] + partial[3]) + 1.0f;
    dinv[row] = 1.0f / sqrtf(deg + 1e-8f);
  }
}

// ---- kernel 2: yT[f][i] = dinv[i] * x[i][f]  (bf16, transposed for NT GEMM) ----
__global__ __launch_bounds__(256) void k_scale_t(const float* __restrict__ x,
                                                 const float* __restrict__ dinv,
                                                 short* __restrict__ yT) {
  __shared__ float tile[64][129];
  const int r0 = blockIdx.x * 64;
  const int tid = threadIdx.x;
#pragma unroll
  for (int it = 0; it < 8; ++it) {
    int q = it * 256 + tid;
    int r = q >> 5;
    int c = q & 31;
    float4 v = ((const float4*)(x + (size_t)(r0 + r) * FF))[c];
    float d = dinv[r0 + r];
    tile[r][c * 4 + 0] = v.x * d;
    tile[r][c * 4 + 1] = v.y * d;
    tile[r][c * 4 + 2] = v.z * d;
    tile[r][c * 4 + 3] = v.w * d;
  }
  __syncthreads();
  const int f = tid >> 1;
  const int i0 = (tid & 1) * 32;
#pragma unroll
  for (int g = 0; g < 4; ++g) {
    bf16x8 o;
#pragma unroll
    for (int j = 0; j < 8; ++j) o[j] = f2bf(tile[i0 + g * 8 + j][f]);
    *(bf16x8*)(yT + (size_t)f * NN + r0 + i0 + g * 8) = o;
  }
}

// ---- kernel 3: zpart[ks] = adj[:, ksliced] @ y. K-split MFMA GEMM. ----
// 1024 blocks (128 M-tiles x 8 K-slices), 512 thr = 8 waves (2M x 4N),
// BM=64, BN=128(all), BK=64. Single-LDS-buffer + 2-deep register prefetch:
// tile loaded at step i is staged at step i+2 -> ~2 steps of latency cover,
// and 2 blocks/CU (LDS 27.6KB, VGPR<=128) overlap each other's stalls.
__global__ __launch_bounds__(512, 4) void k_gemm(const float* __restrict__ adj,
                                                 const short* __restrict__ yT,
                                                 float* __restrict__ zpart) {
  __shared__ short As[BM][72];     // bf16, +8 pad
  __shared__ short Bs[128][72];
  const int tid = threadIdx.x;
  const int wave = tid >> 6;
  const int lane = tid & 63;
  const int mb = 127 - (int)(blockIdx.x & 127);   // reverse: read L3-warm rows first
  const int ks = blockIdx.x >> 7;
  const int row0 = mb * BM;
  const size_t kbase = (size_t)ks * KCH;

  // staging maps: A = 64 rows x 64 f32 (8 f32/thread); B = 128 rows x 64 bf16
  const int s_ar = tid >> 3;
  const int s_ac = (tid & 7) * 8;
  const float* pa = adj + (size_t)(row0 + s_ar) * NN + kbase + s_ac;
  const int s_br = tid >> 3;
  const int s_bc = (tid & 7) * 8;
  const short* pb0 = yT + (size_t)s_br * NN + kbase + s_bc;
  const short* pb1 = yT + (size_t)(s_br + 64) * NN + kbase + s_bc;

  const int wm = (wave >> 2) * 32;   // 0/32
  const int wn = (wave & 3) * 32;    // 0/32/64/96
  const int fr = lane & 15;
  const int kh = (lane >> 4) * 8;

  f32x4 acc00 = {0.f,0.f,0.f,0.f}, acc01 = acc00, acc10 = acc00, acc11 = acc00;

  float4 aXlo, aXhi, aYlo, aYhi;
  bf16x8 bX0, bX1, bY0, bY1;

#define LOADT(alo, ahi, b0v, b1v, koff) do {                                   \
    alo = *(const float4*)(pa + (koff));                                       \
    ahi = *(const float4*)(pa + (koff) + 4);                                   \
    b0v = *(const bf16x8*)(pb0 + (koff));                                      \
    b1v = *(const bf16x8*)(pb1 + (koff));                                      \
  } while (0)

#define STAGE(alo, ahi, b0v, b1v) do {                                         \
    bf16x8 ap_;                                                                \
    ap_[0] = f2bf(alo.x); ap_[1] = f2bf(alo.y);                                \
    ap_[2] = f2bf(alo.z); ap_[3] = f2bf(alo.w);                                \
    ap_[4] = f2bf(ahi.x); ap_[5] = f2bf(ahi.y);                                \
    ap_[6] = f2bf(ahi.z); ap_[7] = f2bf(ahi.w);                                \
    *(bf16x8*)&As[s_ar][s_ac] = ap_;                                           \
    *(bf16x8*)&Bs[s_br][s_bc] = b0v;                                           \
    *(bf16x8*)&Bs[s_br + 64][s_bc] = b1v;                                      \
  } while (0)

#define COMPUTE() do {                                                         \
    _Pragma("unroll")                                                          \
    for (int kk = 0; kk < 2; ++kk) {                                           \
      bf16x8 a0 = *(const bf16x8*)&As[wm + fr][kk * 32 + kh];                  \
      bf16x8 a1 = *(const bf16x8*)&As[wm + 16 + fr][kk * 32 + kh];             \
      bf16x8 b0 = *(const bf16x8*)&Bs[wn + fr][kk * 32 + kh];                  \
      bf16x8 b1 = *(const bf16x8*)&Bs[wn + 16 + fr][kk * 32 + kh];             \
      acc00 = __builtin_amdgcn_mfma_f32_16x16x32_bf16(a0, b0, acc00, 0, 0, 0); \
      acc01 = __builtin_amdgcn_mfma_f32_16x16x32_bf16(a0, b1, acc01, 0, 0, 0); \
      acc10 = __builtin_amdgcn_mfma_f32_16x16x32_bf16(a1, b0, acc10, 0, 0, 0); \
      acc11 = __builtin_amdgcn_mfma_f32_16x16x32_bf16(a1, b1, acc11, 0, 0, 0); \
    }                                                                          \
  } while (0)

  // prologue: tiles 0 and 1 into the two register sets
  LOADT(aXlo, aXhi, bX0, bX1, 0);
  LOADT(aYlo, aYhi, bY0, bY1, BK);

  for (int step = 0; step < NSTEP; step += 2) {
    STAGE(aXlo, aXhi, bX0, bX1);
    __syncthreads();
    if (step + 2 < NSTEP) LOADT(aXlo, aXhi, bX0, bX1, (step + 2) * BK);
    COMPUTE();
    __syncthreads();

    STAGE(aYlo, aYhi, bY0, bY1);
    __syncthreads();
    if (step + 3 < NSTEP) LOADT(aYlo, aYhi, bY0, bY1, (step + 3) * BK);
    COMPUTE();
    __syncthreads();
  }

  // epilogue: D layout col=lane&15, row=(lane>>4)*4+r
  const int r4 = (lane >> 4) * 4;
  float* zp = zpart + ((size_t)ks << 20);   // slice stride 8192*128
#pragma unroll
  for (int r = 0; r < 4; ++r) {
    int gi0 = row0 + wm + r4 + r;
    int gi1 = gi0 + 16;
    zp[(size_t)gi0 * FF + wn + fr]      = acc00[r];
    zp[(size_t)gi0 * FF + wn + 16 + fr] = acc01[r];
    zp[(size_t)gi1 * FF + wn + fr]      = acc10[r];
    zp[(size_t)gi1 * FF + wn + 16 + fr] = acc11[r];
  }
#undef LOADT
#undef STAGE
#undef COMPUTE
}

// ---- kernel 4: out = relu((dinv*(sum_ks zpart + dinv*x)) @ W) ----
__global__ __launch_bounds__(256) void k_out(const float* __restrict__ zpart,
                                             const float* __restrict__ x,
                                             const float* __restrict__ dinv,
                                             const float* __restrict__ w,
                                             float* __restrict__ out) {
  __shared__ float zs[16][128];
  const int r0 = blockIdx.x * 16;
  const int tid = threadIdx.x;
#pragma unroll
  for (int half = 0; half < 2; ++half) {
    int p = half * 256 + tid;
    int r = p >> 5;
    int c4 = p & 31;
    int gi = r0 + r;
    const float* base = zpart + (size_t)gi * FF + c4 * 4;
    float4 s = *(const float4*)base;
#pragma unroll
    for (int sidx = 1; sidx < KS; ++sidx) {
      float4 v = *(const float4*)(base + ((size_t)sidx << 20));
      s.x += v.x; s.y += v.y; s.z += v.z; s.w += v.w;
    }
    float4 xv = *(const float4*)(x + (size_t)gi * FF + c4 * 4);
    float di = dinv[gi];
    float di2 = di * di;
    zs[r][c4 * 4 + 0] = di * s.x + di2 * xv.x;
    zs[r][c4 * 4 + 1] = di * s.y + di2 * xv.y;
    zs[r][c4 * 4 + 2] = di * s.z + di2 * xv.z;
    zs[r][c4 * 4 + 3] = di * s.w + di2 * xv.w;
  }
  __syncthreads();
  const int f = tid & 127;
  const int rg = (tid >> 7) * 8;
  float acc[8] = {0.f, 0.f, 0.f, 0.f, 0.f, 0.f, 0.f, 0.f};
#pragma unroll 4
  for (int k = 0; k < 128; ++k) {
    float wv = w[k * FF + f];
#pragma unroll
    for (int r = 0; r < 8; ++r) acc[r] += zs[rg + r][k] * wv;
  }
#pragma unroll
  for (int r = 0; r < 8; ++r) {
    out[(size_t)(r0 + rg + r) * FF + f] = fmaxf(acc[r], 0.0f);
  }
}

extern "C" void kernel_launch(void* const* d_in, const int* in_sizes, int n_in,
                              void* d_out, int out_size, void* d_ws, size_t ws_size,
                              hipStream_t stream) {
  const float* x   = (const float*)d_in[0];
  const float* adj = (const float*)d_in[1];
  const float* w   = (const float*)d_in[2];
  float* out = (float*)d_out;

  float* dinv  = (float*)d_ws;                                  // 32 KiB @ 0
  short* yT    = (short*)((char*)d_ws + 64 * 1024);             // 2 MiB bf16 [128][8192]
  float* zpart = (float*)((char*)d_ws + 4 * 1024 * 1024);       // 32 MiB f32 [8][8192][128]

  k_deg    <<<NN,      256, 0, stream>>>(adj, dinv);
  k_scale_t<<<NN / 64, 256, 0, stream>>>(x, dinv, yT);
  k_gemm   <<<128 * KS, 512, 0, stream>>>(adj, yT, zpart);
  k_out    <<<NN / 16, 256, 0, stream>>>(zpart, x, dinv, w, out);
}